// Round 8
// baseline (1312.265 us; speedup 1.0000x reference)
//
#include <hip/hip_runtime.h>
#include <hip/hip_fp16.h>
#include <math.h>

#define NEG_SLOPE 0.2f
#define BCAP 6144   // max edges per 256-node bucket (avg ~4350, 27 sigma margin)

typedef short bf16x8 __attribute__((ext_vector_type(8)));
typedef float f32x4 __attribute__((ext_vector_type(4)));

__device__ __forceinline__ unsigned short f2bf(float f) {
  unsigned int u = __builtin_bit_cast(unsigned int, f);
  u = (u + 0x7fffu + ((u >> 16) & 1u)) >> 16;       // RNE, finite data
  return (unsigned short)u;
}
__device__ __forceinline__ unsigned int pk2bf(float lo, float hi) {
  return (unsigned int)f2bf(lo) | ((unsigned int)f2bf(hi) << 16);
}

// ---------- W1 [512][128] fp32 -> Wt [128][512] bf16 (transposed) ----------
__global__ __launch_bounds__(256) void w1conv_kernel(
    const float* __restrict__ W1, unsigned short* __restrict__ Wt)
{
  int idx = blockIdx.x * 256 + threadIdx.x;   // 0..65535 = k*128+n
  int k = idx >> 7, n = idx & 127;
  Wt[n * 512 + k] = f2bf(W1[idx]);
}

// ---------- GEMM1 (MFMA): 64x128 tile, BK=64, reg-prefetch 2-phase ----------
__global__ __launch_bounds__(256) void gemm1_kernel(
    const float* __restrict__ x, const unsigned short* __restrict__ Wt,
    const float* __restrict__ att_src, const float* __restrict__ att_dst,
    __half* __restrict__ h1, float* __restrict__ a_src, float* __restrict__ a_dst,
    int M)
{
  __shared__ unsigned char Asm[64 * 128];    // 64 rows x 64 bf16 (128 B), swizzled
  __shared__ unsigned char Bsm[128 * 128];   // 128 cols x 64 bf16
  const int tid  = threadIdx.x;
  const int lane = tid & 63;
  const int wid  = tid >> 6;
  const int wr   = wid >> 1, wc = wid & 1;   // 2x2 waves: 32 rows x 64 cols each
  const int row0 = blockIdx.x * 64;

  f32x4 acc[2][4];
  #pragma unroll
  for (int m = 0; m < 2; ++m)
    #pragma unroll
    for (int n = 0; n < 4; ++n) acc[m][n] = (f32x4){0.f, 0.f, 0.f, 0.f};

  const int arow = tid >> 2;            // 0..63
  const int akq  = (tid & 3) * 16;      // 16 floats per thread
  const int aswz = (arow & 7) << 4;
  const int brow = tid >> 1;            // 0..127 (column of W)
  const int bkh  = (tid & 1) * 32;      // 32 bf16 = 64 B per thread
  const int bswz = (brow & 7) << 4;
  const bool avalid = (row0 + arow) < M;
  const float4* xbase = (const float4*)&x[(size_t)(row0 + arow) * 512];

  float4 pa[4];
  uint4  pb[4];
  // prefetch tile k0=0
  #pragma unroll
  for (int q = 0; q < 4; ++q)
    pa[q] = avalid ? xbase[(akq >> 2) + q] : make_float4(0.f, 0.f, 0.f, 0.f);
  {
    const uint4* wb = (const uint4*)&Wt[(size_t)brow * 512 + bkh];
    #pragma unroll
    for (int q = 0; q < 4; ++q) pb[q] = wb[q];
  }

  for (int k0 = 0; k0 < 512; k0 += 64) {
    // write prefetched regs to LDS (cvt fp32->bf16 for A)
    uint4 ua = make_uint4(pk2bf(pa[0].x, pa[0].y), pk2bf(pa[0].z, pa[0].w),
                          pk2bf(pa[1].x, pa[1].y), pk2bf(pa[1].z, pa[1].w));
    uint4 ub = make_uint4(pk2bf(pa[2].x, pa[2].y), pk2bf(pa[2].z, pa[2].w),
                          pk2bf(pa[3].x, pa[3].y), pk2bf(pa[3].z, pa[3].w));
    *(uint4*)(Asm + arow * 128 + (((akq    ) * 2) ^ aswz)) = ua;
    *(uint4*)(Asm + arow * 128 + (((akq + 8) * 2) ^ aswz)) = ub;
    #pragma unroll
    for (int q = 0; q < 4; ++q)
      *(uint4*)(Bsm + brow * 128 + (((bkh + q * 8) * 2) ^ bswz)) = pb[q];
    __syncthreads();
    // issue next-tile prefetch (latency hides under compute below)
    if (k0 < 448) {
      int kn = k0 + 64;
      #pragma unroll
      for (int q = 0; q < 4; ++q)
        pa[q] = avalid ? xbase[((kn + akq) >> 2) + q] : make_float4(0.f, 0.f, 0.f, 0.f);
      const uint4* wb = (const uint4*)&Wt[(size_t)brow * 512 + kn + bkh];
      #pragma unroll
      for (int q = 0; q < 4; ++q) pb[q] = wb[q];
    }
    // compute on staged LDS
    #pragma unroll
    for (int ks = 0; ks < 2; ++ks) {
      const int kb = ks * 64 + ((lane >> 4) * 16);
      bf16x8 af[2], bfr[4];
      #pragma unroll
      for (int m = 0; m < 2; ++m) {
        int r = wr * 32 + m * 16 + (lane & 15);
        af[m] = *(const bf16x8*)(Asm + r * 128 + (kb ^ ((r & 7) << 4)));
      }
      #pragma unroll
      for (int n = 0; n < 4; ++n) {
        int r = wc * 64 + n * 16 + (lane & 15);
        bfr[n] = *(const bf16x8*)(Bsm + r * 128 + (kb ^ ((r & 7) << 4)));
      }
      #pragma unroll
      for (int m = 0; m < 2; ++m)
        #pragma unroll
        for (int n = 0; n < 4; ++n)
          acc[m][n] = __builtin_amdgcn_mfma_f32_16x16x32_bf16(af[m], bfr[n], acc[m][n], 0, 0, 0);
    }
    __syncthreads();
  }

  // epilogue: h1 fp16 + per-head a_src/a_dst (head = 16 cols = one n-fragment)
  float asv[4], adv[4];
  #pragma unroll
  for (int n = 0; n < 4; ++n) {
    int col = wc * 64 + n * 16 + (lane & 15);
    asv[n] = att_src[col];
    adv[n] = att_dst[col];
  }
  #pragma unroll
  for (int m = 0; m < 2; ++m) {
    #pragma unroll
    for (int n = 0; n < 4; ++n) {
      const int col  = wc * 64 + n * 16 + (lane & 15);
      const int head = wc * 4 + n;
      #pragma unroll
      for (int e = 0; e < 4; ++e) {
        int row = row0 + wr * 32 + m * 16 + (lane >> 4) * 4 + e;
        float v = acc[m][n][e];
        float ps = v * asv[n], pd = v * adv[n];
        ps += __shfl_xor(ps, 1); pd += __shfl_xor(pd, 1);
        ps += __shfl_xor(ps, 2); pd += __shfl_xor(pd, 2);
        ps += __shfl_xor(ps, 4); pd += __shfl_xor(pd, 4);
        ps += __shfl_xor(ps, 8); pd += __shfl_xor(pd, 8);
        if (row < M) {
          h1[(size_t)row * 128 + col] = __float2half_rn(v);
          if ((lane & 15) == 0) { a_src[row * 8 + head] = ps; a_dst[row * 8 + head] = pd; }
        }
      }
    }
  }
}

// ---------- Bucket sort of edges by dst (391 buckets of 256 nodes) ----------
__global__ __launch_bounds__(256) void bhist_kernel(
    const int* __restrict__ ei, int E, int ET, int* __restrict__ bcnt, int NBUK)
{
  __shared__ int h[512];
  for (int i = threadIdx.x; i < NBUK; i += 256) h[i] = 0;
  __syncthreads();
  for (int e = blockIdx.x * 256 + threadIdx.x; e < ET; e += gridDim.x * 256) {
    int dst = (e < E) ? ei[E + e] : e - E;
    atomicAdd(&h[dst >> 8], 1);
  }
  __syncthreads();
  for (int i = threadIdx.x; i < NBUK; i += 256)
    if (h[i]) atomicAdd(&bcnt[i], h[i]);
}

__global__ __launch_bounds__(512) void bscan_kernel(
    const int* __restrict__ bcnt, int* __restrict__ boff, int* __restrict__ bcur, int NBUK)
{
  __shared__ int sm[512];
  int t = threadIdx.x;
  int v = (t < NBUK) ? bcnt[t] : 0;
  sm[t] = v; __syncthreads();
  #pragma unroll
  for (int o = 1; o < 512; o <<= 1) {
    int a = (t >= o) ? sm[t - o] : 0;
    __syncthreads();
    sm[t] += a;
    __syncthreads();
  }
  if (t < NBUK) {
    int excl = sm[t] - v;
    boff[t] = excl;
    bcur[t] = excl;
    if (t == NBUK - 1) boff[NBUK] = sm[t];
  }
}

// pack (dst&255)<<24 | src ; writes are sequential within each bucket region
__global__ __launch_bounds__(256) void bscatter_kernel(
    const int* __restrict__ ei, int E, int ET,
    int* __restrict__ bcur, int* __restrict__ pairs)
{
  int e = blockIdx.x * 256 + threadIdx.x;
  if (e >= ET) return;
  int src, dst;
  if (e < E) { src = ei[e]; dst = ei[E + e]; }
  else { src = e - E; dst = src; }
  int pos = atomicAdd(&bcur[dst >> 8], 1);
  pairs[pos] = (int)((unsigned)src | ((unsigned)(dst & 255) << 24));
}

// per-bucket LDS counting sort -> ssrc (coalesced) + startp
__global__ __launch_bounds__(256) void bsort_kernel(
    const int* __restrict__ pairs, const int* __restrict__ boff,
    int* __restrict__ ssrc, int* __restrict__ startp, int M, int NBUK)
{
  __shared__ int eloc[BCAP];
  __shared__ int cnt[256];
  __shared__ int cur[256];
  const int b = blockIdx.x;
  const int t = threadIdx.x;
  const int jb = boff[b], je = boff[b + 1];
  int ne = je - jb;
  if (ne > BCAP) ne = BCAP;                 // safety clamp (never expected)
  cnt[t] = 0;
  for (int i = t; i < ne; i += 256) eloc[i] = pairs[jb + i];
  __syncthreads();
  for (int i = t; i < ne; i += 256) atomicAdd(&cnt[((unsigned)eloc[i]) >> 24], 1);
  __syncthreads();
  int v = cnt[t];
  #pragma unroll
  for (int o = 1; o < 256; o <<= 1) {       // in-place Hillis-Steele
    int a = (t >= o) ? cnt[t - o] : 0;
    __syncthreads();
    cnt[t] += a;
    __syncthreads();
  }
  int excl = cnt[t] - v;
  int node = b * 256 + t;
  if (node < M) startp[node] = jb + excl;
  if (b == NBUK - 1 && t == 0) startp[M] = je;
  cur[t] = excl;
  __syncthreads();
  for (int i = t; i < ne; i += 256) {
    int e = eloc[i];
    int pos = atomicAdd(&cur[((unsigned)e) >> 24], 1);
    ssrc[jb + pos] = e & 0xFFFFFF;          // L2-localized (~17 KB window)
  }
}

// ---------- Layer-1 aggregate: 64 thr/node, 2 ch/thread (half2),
//            fused normalize+bias+ELU, fp16 out ----------
__global__ __launch_bounds__(256) void agg1_kernel(
    const int* __restrict__ startp, const int* __restrict__ ssrc,
    const float* __restrict__ a_s, const float* __restrict__ a_d,
    const __half* __restrict__ h1, const float* __restrict__ b1,
    __half* __restrict__ h1e, int M)
{
  int n = blockIdx.x * 4 + (threadIdx.x >> 6);
  if (n >= M) return;
  const int lane = threadIdx.x & 63;
  const int hd = lane >> 3;                  // channels (2*lane, 2*lane+1) -> head
  const __half2* hp = (const __half2*)h1;
  float ad = a_d[n * 8 + hd];
  int jb = startp[n], je = startp[n + 1];
  float acc0 = 0.f, acc1 = 0.f, ssum = 0.f;
  int j = jb;
  for (; j + 3 < je; j += 4) {               // 4-way MLP for the gathers
    int s0 = ssrc[j], s1 = ssrc[j+1], s2 = ssrc[j+2], s3 = ssrc[j+3];
    float e0 = a_s[s0 * 8 + hd] + ad;
    float e1 = a_s[s1 * 8 + hd] + ad;
    float e2 = a_s[s2 * 8 + hd] + ad;
    float e3 = a_s[s3 * 8 + hd] + ad;
    __half2 g0 = hp[(size_t)s0 * 64 + lane];
    __half2 g1 = hp[(size_t)s1 * 64 + lane];
    __half2 g2 = hp[(size_t)s2 * 64 + lane];
    __half2 g3 = hp[(size_t)s3 * 64 + lane];
    e0 = e0 > 0.f ? e0 : NEG_SLOPE * e0;
    e1 = e1 > 0.f ? e1 : NEG_SLOPE * e1;
    e2 = e2 > 0.f ? e2 : NEG_SLOPE * e2;
    e3 = e3 > 0.f ? e3 : NEG_SLOPE * e3;
    float x0 = __expf(e0), x1 = __expf(e1), x2 = __expf(e2), x3 = __expf(e3);
    float2 f0 = __half22float2(g0), f1 = __half22float2(g1);
    float2 f2 = __half22float2(g2), f3 = __half22float2(g3);
    acc0 = fmaf(x0, f0.x, acc0); acc1 = fmaf(x0, f0.y, acc1);
    acc0 = fmaf(x1, f1.x, acc0); acc1 = fmaf(x1, f1.y, acc1);
    acc0 = fmaf(x2, f2.x, acc0); acc1 = fmaf(x2, f2.y, acc1);
    acc0 = fmaf(x3, f3.x, acc0); acc1 = fmaf(x3, f3.y, acc1);
    ssum += (x0 + x1) + (x2 + x3);
  }
  for (; j < je; ++j) {
    int s0 = ssrc[j];
    float e0 = a_s[s0 * 8 + hd] + ad;
    e0 = e0 > 0.f ? e0 : NEG_SLOPE * e0;
    float x0 = __expf(e0);
    float2 f0 = __half22float2(hp[(size_t)s0 * 64 + lane]);
    acc0 = fmaf(x0, f0.x, acc0); acc1 = fmaf(x0, f0.y, acc1);
    ssum += x0;
  }
  float2 bv = *(const float2*)&b1[lane * 2];
  float v0 = acc0 / ssum + bv.x;             // self-loop guarantees ssum > 0
  float v1 = acc1 / ssum + bv.y;
  v0 = v0 > 0.f ? v0 : expm1f(v0);
  v1 = v1 > 0.f ? v1 : expm1f(v1);
  ((__half2*)h1e)[(size_t)n * 64 + lane] = __floats2half2_rn(v0, v1);
}

// ---------- GEMM2: h2 = h1e @ W2 [N,128]x[128,40], fused a2 dots, fp16 out ----------
__global__ __launch_bounds__(256) void gemm2_kernel(
    const __half* __restrict__ h, const float* __restrict__ W2,
    const float* __restrict__ att_src, const float* __restrict__ att_dst,
    __half* __restrict__ h2, float* __restrict__ a2s, float* __restrict__ a2d,
    int M)
{
  __shared__ float W2s[128 * 40];   // 20 KB, whole W2
  __shared__ float hs[4][128];
  const int tid = threadIdx.x;
  const int lane = tid & 63;
  const int w = tid >> 6;
  const __half2* hp = (const __half2*)h;
  for (int i = tid; i < 128 * 40; i += 256) W2s[i] = W2[i];
  float asv = (lane < 40) ? att_src[lane] : 0.f;
  float adv = (lane < 40) ? att_dst[lane] : 0.f;
  __syncthreads();
  for (int r0 = blockIdx.x * 4; r0 < M; r0 += gridDim.x * 4) {
    {
      int r = r0 + (tid >> 6);
      int cp = tid & 63;
      float2 f = make_float2(0.f, 0.f);
      if (r < M) f = __half22float2(hp[(size_t)r * 64 + cp]);
      hs[tid >> 6][cp * 2] = f.x; hs[tid >> 6][cp * 2 + 1] = f.y;
    }
    __syncthreads();
    const int row = r0 + w;
    float acc = 0.f;
    if (lane < 40) {
      #pragma unroll 8
      for (int k = 0; k < 128; ++k) acc = fmaf(hs[w][k], W2s[k * 40 + lane], acc);
    }
    float ps = acc * asv, pd = acc * adv;
    #pragma unroll
    for (int off = 32; off; off >>= 1) { ps += __shfl_xor(ps, off); pd += __shfl_xor(pd, off); }
    if (row < M) {
      if (lane < 40) h2[(size_t)row * 40 + lane] = __float2half_rn(acc);
      if (lane == 0) { a2s[row] = ps; a2d[row] = pd; }
    }
    __syncthreads();
  }
}

// ---------- Layer-2 aggregate: 32 lanes/node, 2 ch/thread,
//            fused normalize+bias+log_softmax ----------
__global__ __launch_bounds__(256) void agg2_kernel(
    const int* __restrict__ startp, const int* __restrict__ ssrc,
    const float* __restrict__ a2s, const float* __restrict__ a2d,
    const __half* __restrict__ h2, const float* __restrict__ b2,
    float* __restrict__ outp, int M)
{
  int n = blockIdx.x * 8 + (threadIdx.x >> 5);
  if (n >= M) return;
  const int l = threadIdx.x & 31;
  const bool act = l < 20;
  const __half2* hp = (const __half2*)h2;    // row = 20 half2
  float ad = a2d[n];
  int jb = startp[n], je = startp[n + 1];
  float acc0 = 0.f, acc1 = 0.f, ssum = 0.f;
  __half2 z2 = __floats2half2_rn(0.f, 0.f);
  int j = jb;
  for (; j + 3 < je; j += 4) {
    int s0 = ssrc[j], s1 = ssrc[j+1], s2 = ssrc[j+2], s3 = ssrc[j+3];
    float e0 = a2s[s0] + ad;
    float e1 = a2s[s1] + ad;
    float e2 = a2s[s2] + ad;
    float e3 = a2s[s3] + ad;
    __half2 g0 = act ? hp[(size_t)s0 * 20 + l] : z2;
    __half2 g1 = act ? hp[(size_t)s1 * 20 + l] : z2;
    __half2 g2 = act ? hp[(size_t)s2 * 20 + l] : z2;
    __half2 g3 = act ? hp[(size_t)s3 * 20 + l] : z2;
    e0 = e0 > 0.f ? e0 : NEG_SLOPE * e0;
    e1 = e1 > 0.f ? e1 : NEG_SLOPE * e1;
    e2 = e2 > 0.f ? e2 : NEG_SLOPE * e2;
    e3 = e3 > 0.f ? e3 : NEG_SLOPE * e3;
    float x0 = __expf(e0), x1 = __expf(e1), x2 = __expf(e2), x3 = __expf(e3);
    float2 f0 = __half22float2(g0), f1 = __half22float2(g1);
    float2 f2 = __half22float2(g2), f3 = __half22float2(g3);
    acc0 = fmaf(x0, f0.x, acc0); acc1 = fmaf(x0, f0.y, acc1);
    acc0 = fmaf(x1, f1.x, acc0); acc1 = fmaf(x1, f1.y, acc1);
    acc0 = fmaf(x2, f2.x, acc0); acc1 = fmaf(x2, f2.y, acc1);
    acc0 = fmaf(x3, f3.x, acc0); acc1 = fmaf(x3, f3.y, acc1);
    ssum += (x0 + x1) + (x2 + x3);
  }
  for (; j < je; ++j) {
    int s0 = ssrc[j];
    float e0 = a2s[s0] + ad;
    e0 = e0 > 0.f ? e0 : NEG_SLOPE * e0;
    float x0 = __expf(e0);
    float2 f0 = __half22float2(act ? hp[(size_t)s0 * 20 + l] : z2);
    acc0 = fmaf(x0, f0.x, acc0); acc1 = fmaf(x0, f0.y, acc1);
    ssum += x0;
  }
  float v0 = act ? acc0 / ssum + b2[l * 2]     : -1e30f;
  float v1 = act ? acc1 / ssum + b2[l * 2 + 1] : -1e30f;
  // log_softmax over 40 classes held as 2 values x 20 lanes (within 32-lane group)
  float m = fmaxf(v0, v1);
  #pragma unroll
  for (int o = 16; o; o >>= 1) m = fmaxf(m, __shfl_xor(m, o));
  float ex = act ? expf(v0 - m) + expf(v1 - m) : 0.f;
  #pragma unroll
  for (int o = 16; o; o >>= 1) ex += __shfl_xor(ex, o);
  float lg = m + logf(ex);
  if (act) *(float2*)&outp[(size_t)n * 40 + l * 2] = make_float2(v0 - lg, v1 - lg);
}

extern "C" void kernel_launch(void* const* d_in, const int* in_sizes, int n_in,
                              void* d_out, int out_size, void* d_ws, size_t ws_size,
                              hipStream_t stream)
{
  const float* x   = (const float*)d_in[0];
  const int*   ei  = (const int*)d_in[1];
  const float* W1  = (const float*)d_in[2];
  const float* as1 = (const float*)d_in[3];
  const float* ad1 = (const float*)d_in[4];
  const float* b1  = (const float*)d_in[5];
  const float* W2  = (const float*)d_in[6];
  const float* as2 = (const float*)d_in[7];
  const float* ad2 = (const float*)d_in[8];
  const float* b2  = (const float*)d_in[9];
  float* outp = (float*)d_out;

  const int M    = in_sizes[0] / 512;    // 100000
  const int E    = in_sizes[1] / 2;      // 1600000
  const int ET   = E + M;                // + self loops
  const int NBUK = (M + 255) >> 8;       // 391 buckets

  __half* h1  = (__half*)d_ws;              // M*128 fp16
  __half* h1e = h1 + (size_t)M * 128;       // M*128 fp16
  __half* h2  = h1e + (size_t)M * 128;      // M*40 fp16
  float* a_s1 = (float*)(h2 + (size_t)M * 40);
  float* a_d1 = a_s1 + (size_t)M * 8;
  float* a2s  = a_d1 + (size_t)M * 8;
  float* a2d  = a2s + M;
  int* startp = (int*)(a2d + M);            // M+1
  int* bcnt   = startp + (M + 1);           // NBUK
  int* boff   = bcnt + NBUK;                // NBUK+1
  int* bcur   = boff + (NBUK + 1);          // NBUK
  int* pairs  = bcur + NBUK;                // ET
  int* ssrc   = pairs + ET;                 // ET
  unsigned short* Wt = (unsigned short*)(ssrc + ET);  // 128*512 bf16

  hipMemsetAsync(bcnt, 0, (size_t)NBUK * sizeof(int), stream);

  // bucket sort by dst (reused by both layers)
  bhist_kernel<<<1024, 256, 0, stream>>>(ei, E, ET, bcnt, NBUK);
  bscan_kernel<<<1, 512, 0, stream>>>(bcnt, boff, bcur, NBUK);
  bscatter_kernel<<<(ET + 255) / 256, 256, 0, stream>>>(ei, E, ET, bcur, pairs);
  bsort_kernel<<<NBUK, 256, 0, stream>>>(pairs, boff, ssrc, startp, M, NBUK);

  // layer 1
  w1conv_kernel<<<256, 256, 0, stream>>>(W1, Wt);
  gemm1_kernel<<<(M + 63) / 64, 256, 0, stream>>>(x, Wt, as1, ad1, h1, a_s1, a_d1, M);
  agg1_kernel<<<(M + 3) / 4, 256, 0, stream>>>(startp, ssrc, a_s1, a_d1, h1, b1, h1e, M);

  // layer 2
  gemm2_kernel<<<1024, 256, 0, stream>>>(h1e, W2, as2, ad2, h2, a2s, a2d, M);
  agg2_kernel<<<(M + 7) / 8, 256, 0, stream>>>(startp, ssrc, a2s, a2d, h2, b2, outp, M);
}